// Round 3
// baseline (338.274 us; speedup 1.0000x reference)
//
#include <hip/hip_runtime.h>

// DiffUnpool: out[b] = S[b] @ x[b]
// B=16, N_orig(M)=2048, N_pool(K)=256, C(N)=256, fp32 in/out. A unused.
#define NB 16
#define NO 2048   // M
#define NP 256    // K
#define CC 256    // N

typedef float  f32x4  __attribute__((ext_vector_type(4)));
typedef short  bf16x8 __attribute__((ext_vector_type(8)));
typedef unsigned int   u32x4 __attribute__((ext_vector_type(4)));
typedef unsigned short u16x4 __attribute__((ext_vector_type(4)));

__device__ __forceinline__ unsigned short f2bf(float f) {
    unsigned int u = __float_as_uint(f);
    u += 0x7fffu + ((u >> 16) & 1u);   // round-to-nearest-even
    return (unsigned short)(u >> 16);
}
__device__ __forceinline__ float bf2f(unsigned short s) {
    return __uint_as_float(((unsigned int)s) << 16);
}

// ---------------------------------------------------------------------------
// Kernel 1: x[b][p][c] fp32  ->  xt_hi/xt_lo [b][c][p] bf16 (transposed split)
// 64x64 tiles via padded-LDS transpose. grid = (CC/64, NP/64, NB), block 256.
// ---------------------------------------------------------------------------
__global__ __launch_bounds__(256)
void xpose_split_kernel(const float* __restrict__ x,
                        unsigned short* __restrict__ xth,
                        unsigned short* __restrict__ xtl) {
    __shared__ float tile[64][65];           // +1 pad breaks bank conflicts
    const int c0 = blockIdx.x * 64;
    const int p0 = blockIdx.y * 64;
    const int b  = blockIdx.z;
    const int t  = threadIdx.x;

    const float* xb = x + ((size_t)b * NP + p0) * CC + c0;
    const int c4 = t & 15;        // float4 index within a 64-col row
    const int r0 = t >> 4;        // row base (16 rows per pass)
#pragma unroll
    for (int i = 0; i < 4; ++i) {
        const int p = r0 + 16 * i;
        f32x4 v = *(const f32x4*)(xb + (size_t)p * CC + c4 * 4);
        tile[p][c4 * 4 + 0] = v.x;
        tile[p][c4 * 4 + 1] = v.y;
        tile[p][c4 * 4 + 2] = v.z;
        tile[p][c4 * 4 + 3] = v.w;
    }
    __syncthreads();

    const int p4 = t & 15;        // 4 consecutive p values per thread
    const int cb = t >> 4;        // c row base (16 rows per pass)
#pragma unroll
    for (int i = 0; i < 4; ++i) {
        const int c = cb + 16 * i;
        u16x4 hi, lo;
#pragma unroll
        for (int j = 0; j < 4; ++j) {
            const float f = tile[p4 * 4 + j][c];
            const unsigned short h = f2bf(f);
            hi[j] = h;
            lo[j] = f2bf(f - bf2f(h));
        }
        const size_t o = ((size_t)b * CC + c0 + c) * NP + p0 + p4 * 4;
        *(u16x4*)(xth + o) = hi;
        *(u16x4*)(xtl + o) = lo;
    }
}

// ---------------------------------------------------------------------------
// Kernel 2: GEMM out[b] = S[b] @ x[b] via bf16x3 split MFMA.
// Tile BM=128, BN=128, BK=64. 256 threads = 4 waves (2x2), wave tile 64x64.
// LDS: 4 x [128][64] bf16 tiles (A_hi, A_lo, B_hi, B_lo), XOR-swizzled.
// grid = (CC/128, NO/128, NB), block 256.
// ---------------------------------------------------------------------------
__global__ __launch_bounds__(256)
void unpool_gemm_kernel(const float* __restrict__ S,
                        const unsigned short* __restrict__ xth,
                        const unsigned short* __restrict__ xtl,
                        float* __restrict__ out) {
    const int bx = blockIdx.x;          // N-block (0..1)
    const int by = blockIdx.y;          // M-block (0..15)
    const int b  = blockIdx.z;          // batch
    const int t    = threadIdx.x;
    const int lane = t & 63;
    const int wid  = t >> 6;
    const int wm   = wid >> 1;          // 0..1
    const int wn   = wid & 1;           // 0..1

    __shared__ unsigned short sAh[128 * 64];
    __shared__ unsigned short sAl[128 * 64];
    __shared__ unsigned short sBh[128 * 64];
    __shared__ unsigned short sBl[128 * 64];

    const float*          Sblk = S   + ((size_t)b * NO + by * 128) * NP;
    const unsigned short* Bhp  = xth + ((size_t)b * CC + bx * 128) * NP;
    const unsigned short* Blp  = xtl + ((size_t)b * CC + bx * 128) * NP;

    // staging maps
    const int a_k4 = t & 15;   // float4 idx in 64-wide k row
    const int a_r0 = t >> 4;   // A row base, rows a_r0 + 16*i, i<8
    const int b_k8 = t & 7;    // 16B chunk idx in 64-wide k row
    const int b_n0 = t >> 3;   // B row base, rows b_n0 + 32*i, i<4

    f32x4 aS[8];
    u32x4 bSh[4], bSl[4];

#define LOAD_A(kt)                                                          \
    {                                                                       \
        _Pragma("unroll") for (int i = 0; i < 8; ++i)                       \
            aS[i] = *(const f32x4*)(Sblk + (size_t)(a_r0 + 16 * i) * NP +   \
                                    (kt) * 64 + a_k4 * 4);                  \
    }
#define LOAD_B(kt)                                                          \
    {                                                                       \
        _Pragma("unroll") for (int i = 0; i < 4; ++i) {                     \
            const size_t o = (size_t)(b_n0 + 32 * i) * NP + (kt) * 64 +     \
                             b_k8 * 8;                                      \
            bSh[i] = *(const u32x4*)(Bhp + o);                              \
            bSl[i] = *(const u32x4*)(Blp + o);                              \
        }                                                                   \
    }

    f32x4 acc[4][4];
#pragma unroll
    for (int m = 0; m < 4; ++m)
#pragma unroll
        for (int n = 0; n < 4; ++n) acc[m][n] = (f32x4)0.0f;

    LOAD_A(0);
    LOAD_B(0);

    for (int kt = 0; kt < 4; ++kt) {
        if (kt) __syncthreads();        // prior iter's ds_reads done

        // convert + write A tile (swizzled)
#pragma unroll
        for (int i = 0; i < 8; ++i) {
            const int r = a_r0 + 16 * i;
            u16x4 hi, lo;
#pragma unroll
            for (int j = 0; j < 4; ++j) {
                const float f = aS[i][j];
                const unsigned short h = f2bf(f);
                hi[j] = h;
                lo[j] = f2bf(f - bf2f(h));
            }
            const int off = (r * 128 + a_k4 * 8) ^ ((r & 7) << 4);
            *(u16x4*)((char*)sAh + off) = hi;
            *(u16x4*)((char*)sAl + off) = lo;
        }
        // write B tile (already bf16, swizzled)
#pragma unroll
        for (int i = 0; i < 4; ++i) {
            const int n = b_n0 + 32 * i;
            const int off = (n * 128 + b_k8 * 16) ^ ((n & 7) << 4);
            *(u32x4*)((char*)sBh + off) = bSh[i];
            *(u32x4*)((char*)sBl + off) = bSl[i];
        }

        if (kt < 3) { LOAD_A(kt + 1); LOAD_B(kt + 1); }  // reg prefetch

        __syncthreads();

        // fragments + MFMA
#pragma unroll
        for (int ks = 0; ks < 2; ++ks) {
            bf16x8 ah[4], al[4], bh[4], bl[4];
            const int kb = (ks * 32 + (lane >> 4) * 8) * 2;  // byte offset in k
#pragma unroll
            for (int m = 0; m < 4; ++m) {
                const int row = wm * 64 + m * 16 + (lane & 15);
                const int off = (row * 128 + kb) ^ ((row & 7) << 4);
                ah[m] = *(const bf16x8*)((char*)sAh + off);
                al[m] = *(const bf16x8*)((char*)sAl + off);
            }
#pragma unroll
            for (int n = 0; n < 4; ++n) {
                const int col = wn * 64 + n * 16 + (lane & 15);
                const int off = (col * 128 + kb) ^ ((col & 7) << 4);
                bh[n] = *(const bf16x8*)((char*)sBh + off);
                bl[n] = *(const bf16x8*)((char*)sBl + off);
            }
#pragma unroll
            for (int m = 0; m < 4; ++m)
#pragma unroll
                for (int n = 0; n < 4; ++n) {
                    acc[m][n] = __builtin_amdgcn_mfma_f32_16x16x32_bf16(
                        ah[m], bh[n], acc[m][n], 0, 0, 0);
                    acc[m][n] = __builtin_amdgcn_mfma_f32_16x16x32_bf16(
                        ah[m], bl[n], acc[m][n], 0, 0, 0);
                    acc[m][n] = __builtin_amdgcn_mfma_f32_16x16x32_bf16(
                        al[m], bh[n], acc[m][n], 0, 0, 0);
                }
        }
    }

    // epilogue: C/D layout col = lane&15, row = (lane>>4)*4 + reg
    float* Ob = out + ((size_t)b * NO + by * 128 + wm * 64) * CC +
                bx * 128 + wn * 64;
    const int r0e = (lane >> 4) * 4;
    const int c0e = lane & 15;
#pragma unroll
    for (int m = 0; m < 4; ++m)
#pragma unroll
        for (int n = 0; n < 4; ++n)
#pragma unroll
            for (int r = 0; r < 4; ++r)
                Ob[(size_t)(m * 16 + r0e + r) * CC + n * 16 + c0e] =
                    acc[m][n][r];
#undef LOAD_A
#undef LOAD_B
}

extern "C" void kernel_launch(void* const* d_in, const int* in_sizes, int n_in,
                              void* d_out, int out_size, void* d_ws, size_t ws_size,
                              hipStream_t stream) {
    const float* x = (const float*)d_in[0];   // [16][256][256]
    const float* S = (const float*)d_in[1];   // [16][2048][256]
    // d_in[2] = A, unused by the reference
    float* out = (float*)d_out;               // [16][2048][256]

    unsigned short* xth = (unsigned short*)d_ws;                    // 2 MB
    unsigned short* xtl = xth + (size_t)NB * CC * NP;               // 2 MB

    dim3 g1(CC / 64, NP / 64, NB);   // (4,4,16)
    xpose_split_kernel<<<g1, 256, 0, stream>>>(x, xth, xtl);

    dim3 g2(CC / 128, NO / 128, NB); // (2,16,16)
    unpool_gemm_kernel<<<g2, 256, 0, stream>>>(S, xth, xtl, out);
}

// Round 6
// 337.656 us; speedup vs baseline: 1.0018x; 1.0018x over previous
//
#include <hip/hip_runtime.h>

// DiffUnpool: out[b] = S[b] @ x[b]
// B=16, N_orig(M)=2048, N_pool(K)=256, C(N)=256, fp32 in/out. A unused.
#define NB 16
#define NO 2048   // M
#define NP 256    // K
#define CC 256    // N

typedef float  f32x4  __attribute__((ext_vector_type(4)));
typedef short  bf16x8 __attribute__((ext_vector_type(8)));
typedef unsigned int   u32x4 __attribute__((ext_vector_type(4)));
typedef unsigned short u16x4 __attribute__((ext_vector_type(4)));

__device__ __forceinline__ unsigned short f2bf(float f) {
    unsigned int u = __float_as_uint(f);
    u += 0x7fffu + ((u >> 16) & 1u);   // round-to-nearest-even
    return (unsigned short)(u >> 16);
}
__device__ __forceinline__ float bf2f(unsigned short s) {
    return __uint_as_float(((unsigned int)s) << 16);
}

// ---------------------------------------------------------------------------
// Kernel 1: x[b][p][c] fp32  ->  xt_hi/xt_lo [b][c][p] bf16 (transposed split)
// 64x64 tiles via padded-LDS transpose. grid = (CC/64, NP/64, NB), block 256.
// ---------------------------------------------------------------------------
__global__ __launch_bounds__(256)
void xpose_split_kernel(const float* __restrict__ x,
                        unsigned short* __restrict__ xth,
                        unsigned short* __restrict__ xtl) {
    __shared__ float tile[64][65];           // +1 pad breaks bank conflicts
    const int c0 = blockIdx.x * 64;
    const int p0 = blockIdx.y * 64;
    const int b  = blockIdx.z;
    const int t  = threadIdx.x;

    const float* xb = x + ((size_t)b * NP + p0) * CC + c0;
    const int c4 = t & 15;        // float4 index within a 64-col row
    const int r0 = t >> 4;        // row base (16 rows per pass)
#pragma unroll
    for (int i = 0; i < 4; ++i) {
        const int p = r0 + 16 * i;
        f32x4 v = *(const f32x4*)(xb + (size_t)p * CC + c4 * 4);
        tile[p][c4 * 4 + 0] = v.x;
        tile[p][c4 * 4 + 1] = v.y;
        tile[p][c4 * 4 + 2] = v.z;
        tile[p][c4 * 4 + 3] = v.w;
    }
    __syncthreads();

    const int p4 = t & 15;        // 4 consecutive p values per thread
    const int cb = t >> 4;        // c row base (16 rows per pass)
#pragma unroll
    for (int i = 0; i < 4; ++i) {
        const int c = cb + 16 * i;
        u16x4 hi, lo;
#pragma unroll
        for (int j = 0; j < 4; ++j) {
            const float f = tile[p4 * 4 + j][c];
            const unsigned short h = f2bf(f);
            hi[j] = h;
            lo[j] = f2bf(f - bf2f(h));
        }
        const size_t o = ((size_t)b * CC + c0 + c) * NP + p0 + p4 * 4;
        *(u16x4*)(xth + o) = hi;
        *(u16x4*)(xtl + o) = lo;
    }
}

// ---------------------------------------------------------------------------
// Kernel 2: GEMM out[b] = S[b] @ x[b] via bf16x4 split MFMA
// (hi*hi + hi*lo + lo*hi + lo*lo).
// Tile BM=128, BN=128, BK=64. 256 threads = 4 waves (2x2), wave tile 64x64.
// LDS: 4 x [128][64] bf16 tiles (A_hi, A_lo, B_hi, B_lo), XOR-swizzled.
// grid = (CC/128, NO/128, NB), block 256.
// ---------------------------------------------------------------------------
__global__ __launch_bounds__(256)
void unpool_gemm_kernel(const float* __restrict__ S,
                        const unsigned short* __restrict__ xth,
                        const unsigned short* __restrict__ xtl,
                        float* __restrict__ out) {
    const int bx = blockIdx.x;          // N-block (0..1)
    const int by = blockIdx.y;          // M-block (0..15)
    const int b  = blockIdx.z;          // batch
    const int t    = threadIdx.x;
    const int lane = t & 63;
    const int wid  = t >> 6;
    const int wm   = wid >> 1;          // 0..1
    const int wn   = wid & 1;           // 0..1

    __shared__ unsigned short sAh[128 * 64];
    __shared__ unsigned short sAl[128 * 64];
    __shared__ unsigned short sBh[128 * 64];
    __shared__ unsigned short sBl[128 * 64];

    const float*          Sblk = S   + ((size_t)b * NO + by * 128) * NP;
    const unsigned short* Bhp  = xth + ((size_t)b * CC + bx * 128) * NP;
    const unsigned short* Blp  = xtl + ((size_t)b * CC + bx * 128) * NP;

    // staging maps
    const int a_k4 = t & 15;   // float4 idx in 64-wide k row
    const int a_r0 = t >> 4;   // A row base, rows a_r0 + 16*i, i<8
    const int b_k8 = t & 7;    // 16B chunk idx in 64-wide k row
    const int b_n0 = t >> 3;   // B row base, rows b_n0 + 32*i, i<4

    f32x4 aS[8];
    u32x4 bSh[4], bSl[4];

#define LOAD_A(kt)                                                          \
    {                                                                       \
        _Pragma("unroll") for (int i = 0; i < 8; ++i)                       \
            aS[i] = *(const f32x4*)(Sblk + (size_t)(a_r0 + 16 * i) * NP +   \
                                    (kt) * 64 + a_k4 * 4);                  \
    }
#define LOAD_B(kt)                                                          \
    {                                                                       \
        _Pragma("unroll") for (int i = 0; i < 4; ++i) {                     \
            const size_t o = (size_t)(b_n0 + 32 * i) * NP + (kt) * 64 +     \
                             b_k8 * 8;                                      \
            bSh[i] = *(const u32x4*)(Bhp + o);                              \
            bSl[i] = *(const u32x4*)(Blp + o);                              \
        }                                                                   \
    }

    f32x4 acc[4][4];
#pragma unroll
    for (int m = 0; m < 4; ++m)
#pragma unroll
        for (int n = 0; n < 4; ++n) acc[m][n] = (f32x4)0.0f;

    LOAD_A(0);
    LOAD_B(0);

    for (int kt = 0; kt < 4; ++kt) {
        if (kt) __syncthreads();        // prior iter's ds_reads done

        // convert + write A tile (swizzled)
#pragma unroll
        for (int i = 0; i < 8; ++i) {
            const int r = a_r0 + 16 * i;
            u16x4 hi, lo;
#pragma unroll
            for (int j = 0; j < 4; ++j) {
                const float f = aS[i][j];
                const unsigned short h = f2bf(f);
                hi[j] = h;
                lo[j] = f2bf(f - bf2f(h));
            }
            const int off = (r * 128 + a_k4 * 8) ^ ((r & 7) << 4);
            *(u16x4*)((char*)sAh + off) = hi;
            *(u16x4*)((char*)sAl + off) = lo;
        }
        // write B tile (already bf16, swizzled)
#pragma unroll
        for (int i = 0; i < 4; ++i) {
            const int n = b_n0 + 32 * i;
            const int off = (n * 128 + b_k8 * 16) ^ ((n & 7) << 4);
            *(u32x4*)((char*)sBh + off) = bSh[i];
            *(u32x4*)((char*)sBl + off) = bSl[i];
        }

        __syncthreads();

        // prefetch next tile AFTER the barrier: the compiler drains
        // vmcnt(0) at each s_barrier, so loads issued here overlap the
        // MFMA block below and drain at the NEXT iteration's barrier.
        if (kt < 3) { LOAD_A(kt + 1); LOAD_B(kt + 1); }

        // fragments + MFMA
#pragma unroll
        for (int ks = 0; ks < 2; ++ks) {
            bf16x8 ah[4], al[4], bh[4], bl[4];
            const int kb = (ks * 32 + (lane >> 4) * 8) * 2;  // byte offset in k
#pragma unroll
            for (int m = 0; m < 4; ++m) {
                const int row = wm * 64 + m * 16 + (lane & 15);
                const int off = (row * 128 + kb) ^ ((row & 7) << 4);
                ah[m] = *(const bf16x8*)((char*)sAh + off);
                al[m] = *(const bf16x8*)((char*)sAl + off);
            }
#pragma unroll
            for (int n = 0; n < 4; ++n) {
                const int col = wn * 64 + n * 16 + (lane & 15);
                const int off = (col * 128 + kb) ^ ((col & 7) << 4);
                bh[n] = *(const bf16x8*)((char*)sBh + off);
                bl[n] = *(const bf16x8*)((char*)sBl + off);
            }
#pragma unroll
            for (int m = 0; m < 4; ++m)
#pragma unroll
                for (int n = 0; n < 4; ++n) {
                    acc[m][n] = __builtin_amdgcn_mfma_f32_16x16x32_bf16(
                        ah[m], bh[n], acc[m][n], 0, 0, 0);
                    acc[m][n] = __builtin_amdgcn_mfma_f32_16x16x32_bf16(
                        ah[m], bl[n], acc[m][n], 0, 0, 0);
                    acc[m][n] = __builtin_amdgcn_mfma_f32_16x16x32_bf16(
                        al[m], bh[n], acc[m][n], 0, 0, 0);
                    acc[m][n] = __builtin_amdgcn_mfma_f32_16x16x32_bf16(
                        al[m], bl[n], acc[m][n], 0, 0, 0);
                }
        }
    }

    // epilogue: C/D layout col = lane&15, row = (lane>>4)*4 + reg
    float* Ob = out + ((size_t)b * NO + by * 128 + wm * 64) * CC +
                bx * 128 + wn * 64;
    const int r0e = (lane >> 4) * 4;
    const int c0e = lane & 15;
#pragma unroll
    for (int m = 0; m < 4; ++m)
#pragma unroll
        for (int n = 0; n < 4; ++n)
#pragma unroll
            for (int r = 0; r < 4; ++r)
                Ob[(size_t)(m * 16 + r0e + r) * CC + n * 16 + c0e] =
                    acc[m][n][r];
#undef LOAD_A
#undef LOAD_B
}

extern "C" void kernel_launch(void* const* d_in, const int* in_sizes, int n_in,
                              void* d_out, int out_size, void* d_ws, size_t ws_size,
                              hipStream_t stream) {
    const float* x = (const float*)d_in[0];   // [16][256][256]
    const float* S = (const float*)d_in[1];   // [16][2048][256]
    // d_in[2] = A, unused by the reference
    float* out = (float*)d_out;               // [16][2048][256]

    unsigned short* xth = (unsigned short*)d_ws;                    // 2 MB
    unsigned short* xtl = xth + (size_t)NB * CC * NP;               // 2 MB

    dim3 g1(CC / 64, NP / 64, NB);   // (4,4,16)
    xpose_split_kernel<<<g1, 256, 0, stream>>>(x, xth, xtl);

    dim3 g2(CC / 128, NO / 128, NB); // (2,16,16)
    unpool_gemm_kernel<<<g2, 256, 0, stream>>>(S, xth, xtl, out);
}